// Round 6
// baseline (203.040 us; speedup 1.0000x reference)
//
#include <hip/hip_runtime.h>
#include <hip/hip_bf16.h>
#include <cstdint>
#include <cstddef>

// ---- types ----
typedef __attribute__((ext_vector_type(8))) short bf8_t;   // 8 x bf16 (4 VGPRs) MFMA A/B frag
typedef __attribute__((ext_vector_type(4))) float f4_t;    // MFMA C/D frag

__device__ __forceinline__ unsigned short f2bf(float f) {
    union { float f; unsigned int u; } v; v.f = f;
    unsigned int u = v.u + 0x7FFFu + ((v.u >> 16) & 1u);   // RNE
    return (unsigned short)(u >> 16);
}

// async global->LDS, 16B per lane. LDS dest = wave-uniform base + lane*16.
__device__ __forceinline__ void gl_lds16(const void* g, void* l) {
    __builtin_amdgcn_global_load_lds(
        (const __attribute__((address_space(1))) unsigned int*)g,
        (__attribute__((address_space(3))) unsigned int*)l,
        16, 0, 0);
}

// ---- fused fp32 -> bf16 convert for x, Wqkv, Wd ----
__global__ void cvt_kernel(const float* __restrict__ x,    unsigned short* __restrict__ xb,
                           const float* __restrict__ wq,   unsigned short* __restrict__ wqb,
                           const float* __restrict__ wd,   unsigned short* __restrict__ wdb) {
    int i = blockIdx.x * blockDim.x + threadIdx.x;          // over float4s, total 2097152
    const float* src; unsigned short* dst; int off;
    if (i < 1048576)       { src = x;  dst = xb;  off = i; }
    else if (i < 1835008)  { src = wq; dst = wqb; off = i - 1048576; }
    else                   { src = wd; dst = wdb; off = i - 1835008; }
    float4 f = ((const float4*)src)[off];
    ushort4 o;
    o.x = f2bf(f.x); o.y = f2bf(f.y); o.z = f2bf(f.z); o.w = f2bf(f.w);
    ((ushort4*)dst)[off] = o;
}

// ---- GEMM: C[M][N] = A[M][K] * W[N][K]^T + bias.  TM=64, TN=128, BK=32 ----
// Staging: one gl_lds16 = 64 lanes x 16 B = 1 KB = 16 rows x 32 bf16 cols.
// Lane layout lrow=lane>>2, lcol=(lane&3)*8 matches the lane-contiguous LDS dest.
// MODE 0: qkv epilogue -> scatter bf16 into q[b,h,s,64], k[b,h,s,64], vT[b,h,64,s]
// MODE 1: proj epilogue -> fp32 out[row*Nn + col]
template<int MODE>
__global__ __launch_bounds__(256, 2) void gemm_bt_kernel(
    const unsigned short* __restrict__ A,
    const unsigned short* __restrict__ W,
    const float* __restrict__ bias,
    float* __restrict__ outf,
    unsigned short* __restrict__ qb,
    unsigned short* __restrict__ kb,
    unsigned short* __restrict__ vtb,
    int K, int Nn)
{
    __shared__ unsigned short As[64][32];    // 4 KB
    __shared__ unsigned short Bs[128][32];   // 8 KB

    const int tid  = threadIdx.x;
    const int lane = tid & 63;
    const int w    = tid >> 6;      // wave 0..3
    const int wm   = w & 1;         // m-half (32 rows)
    const int wn   = w >> 1;        // n-half (64 cols)
    const int quad = lane >> 4;
    const int l16  = lane & 15;
    const int m0   = blockIdx.y * 64;
    const int n0   = blockIdx.x * 128;

    const int lrow = lane >> 2;          // 0..15
    const int lcol = (lane & 3) << 3;    // 0,8,16,24 (bf16 cols)

    f4_t acc[2][4];
    {
        f4_t z = {0.f, 0.f, 0.f, 0.f};
        #pragma unroll
        for (int i = 0; i < 2; ++i)
            #pragma unroll
            for (int j = 0; j < 4; ++j) acc[i][j] = z;
    }

    // A: 64 rows -> 4 instrs -> 1 per wave (rows w*16 + lrow)
    const unsigned short* Ag0 = A + (size_t)(m0 + w * 16 + lrow) * K + lcol;
    // B: 128 rows -> 8 instrs -> 2 per wave (rows w*16 + lrow, 64 + w*16 + lrow)
    const unsigned short* Bg0 = W + (size_t)(n0 + w * 16 + lrow) * K + lcol;
    const unsigned short* Bg1 = W + (size_t)(n0 + 64 + w * 16 + lrow) * K + lcol;
    unsigned short* lA0 = &As[w * 16][0];
    unsigned short* lB0 = &Bs[w * 16][0];
    unsigned short* lB1 = &Bs[64 + w * 16][0];

    for (int kk = 0; kk < K; kk += 32) {
        __syncthreads();                       // all waves done reading LDS
        gl_lds16(Ag0 + kk, lA0);
        gl_lds16(Bg0 + kk, lB0);
        gl_lds16(Bg1 + kk, lB1);
        __syncthreads();                       // drains vmcnt, data visible

        bf8_t af[2], bfr[4];
        #pragma unroll
        for (int mb = 0; mb < 2; ++mb)
            af[mb] = *(const bf8_t*)&As[wm * 32 + mb * 16 + l16][quad * 8];
        #pragma unroll
        for (int nb = 0; nb < 4; ++nb)
            bfr[nb] = *(const bf8_t*)&Bs[wn * 64 + nb * 16 + l16][quad * 8];
        #pragma unroll
        for (int mb = 0; mb < 2; ++mb)
            #pragma unroll
            for (int nb = 0; nb < 4; ++nb)
                acc[mb][nb] = __builtin_amdgcn_mfma_f32_16x16x32_bf16(af[mb], bfr[nb], acc[mb][nb], 0, 0, 0);
    }

    #pragma unroll
    for (int nb = 0; nb < 4; ++nb) {
        const int col = n0 + wn * 64 + nb * 16 + l16;
        const float bc = bias[col];
        const int which  = col >> 10;
        const int within = col & 1023;
        const int head   = within >> 6;
        const int hdi    = within & 63;
        #pragma unroll
        for (int mb = 0; mb < 2; ++mb) {
            #pragma unroll
            for (int r = 0; r < 4; ++r) {
                const int row = m0 + wm * 32 + mb * 16 + quad * 4 + r;
                const float v = acc[mb][nb][r] + bc;
                if (MODE == 0) {
                    const int b  = row >> 11;       // s = 2048
                    const int sq = row & 2047;
                    const int bh = b * 16 + head;
                    const unsigned short bv = f2bf(v);
                    if (which == 0)      qb [((size_t)bh * 2048 + sq) * 64 + hdi] = bv;
                    else if (which == 1) kb [((size_t)bh * 2048 + sq) * 64 + hdi] = bv;
                    else                 vtb[((size_t)bh * 64 + hdi) * 2048 + sq] = bv;
                } else {
                    outf[(size_t)row * Nn + col] = v;
                }
            }
        }
    }
}

// ---- flash attention, causal. Pair-balanced, XCD-swizzled.
// 1-D grid 512: bh = (bx&7)*4 + ((bx>>3)&3) -> each XCD owns 4 bh's (2 MB K/V < 4 MB L2).
// Double-buffered K/V LDS, ONE barrier/tile. Fixed-max softmax (M=14).
__global__ __launch_bounds__(256, 2) void attn_kernel(
    const unsigned short* __restrict__ qg,   // [bh][2048][64]
    const unsigned short* __restrict__ kg,   // [bh][2048][64]
    const unsigned short* __restrict__ vg,   // [bh][64][2048]  (V^T)
    unsigned short* __restrict__ ao)         // [b][sq][head*64+hd] = [4096][1024]
{
    __shared__ unsigned short QP[64][72];       // Q stage -> P (wave-private rows)
    __shared__ unsigned short Ks[2][64][72];
    __shared__ unsigned short Vs[2][64][72];    // [d][sk]

    const int tid  = threadIdx.x;
    const int lane = tid & 63;
    const int w    = tid >> 6;
    const int quad = lane >> 4;
    const int l16  = lane & 15;
    const int bx   = blockIdx.x;            // 0..511
    const int bh   = ((bx & 7) << 2) + ((bx >> 3) & 3);   // XCD-affine bh
    const int jj   = bx >> 5;               // 0..15 pair index
    const int qtBig   = 31 - jj;
    const int qtSmall = jj;
    const int b    = bh >> 4;
    const int head = bh & 15;

    const unsigned short* Qp = qg + (size_t)bh * 2048 * 64;
    const unsigned short* Kp = kg + (size_t)bh * 2048 * 64;
    const unsigned short* Vp = vg + (size_t)bh * 64 * 2048;

    const int sr = tid >> 2;            // 0..63 staging row (wave w -> rows 16w..16w+15)
    const int sc = (tid & 3) << 4;      // 0,16,32,48 shorts

    // prefetch both Q tiles into registers
    float4 q0a = *(const float4*)(Qp + (size_t)(qtBig * 64 + sr) * 64 + sc);
    float4 q0b = *(const float4*)(Qp + (size_t)(qtBig * 64 + sr) * 64 + sc + 8);
    float4 q1a = *(const float4*)(Qp + (size_t)(qtSmall * 64 + sr) * 64 + sc);
    float4 q1b = *(const float4*)(Qp + (size_t)(qtSmall * 64 + sr) * 64 + sc + 8);

    // prefetch K/V tile 0
    float4 k0 = *(const float4*)(Kp + (size_t)sr * 64 + sc);
    float4 k1 = *(const float4*)(Kp + (size_t)sr * 64 + sc + 8);
    float4 v0 = *(const float4*)(Vp + (size_t)sr * 2048 + sc);
    float4 v1 = *(const float4*)(Vp + (size_t)sr * 2048 + sc + 8);

    // stage phase-0 Q; frag rows are wave-private -> no barrier
    *(float4*)&QP[sr][sc]     = q0a;
    *(float4*)&QP[sr][sc + 8] = q0b;
    bf8_t aq[2];
    aq[0] = *(const bf8_t*)&QP[w * 16 + l16][quad * 8];
    aq[1] = *(const bf8_t*)&QP[w * 16 + l16][32 + quad * 8];

    // ones B-fragment: column n=0 all 1.0 -> MFMA row-sum of P
    bf8_t bones;
    {
        const short one = (l16 == 0) ? (short)0x3F80 : (short)0;
        #pragma unroll
        for (int j = 0; j < 8; ++j) bones[j] = one;
    }

    f4_t oacc[4];
    f4_t lacc;
    {
        f4_t z = {0.f, 0.f, 0.f, 0.f};
        #pragma unroll
        for (int j = 0; j < 4; ++j) oacc[j] = z;
        lacc = z;
    }

    auto epilogue = [&](int qt) {
        #pragma unroll
        for (int r = 0; r < 4; ++r) {
            const float lsum = __shfl(lacc[r], lane & 48);   // col 0 of quad
            const float rl = 1.f / lsum;
            const int sq = qt * 64 + (w << 4) + (quad << 2) + r;
            #pragma unroll
            for (int nb = 0; nb < 4; ++nb) {
                const int dcol = head * 64 + nb * 16 + l16;
                ao[((size_t)(b * 2048 + sq)) * 1024 + dcol] = f2bf(oacc[nb][r] * rl);
            }
        }
    };

    const int p0len = 32 - jj;     // tiles in phase 0 (qtBig+1)

    for (int t = 0; t < 33; ++t) {
        const int buf = t & 1;
        // stage K/V from prefetch regs into buf; readers of this buf were at
        // tile t-2 and have passed barrier t-1 -> safe with ONE barrier/tile
        *(float4*)&Ks[buf][sr][sc]     = k0;
        *(float4*)&Ks[buf][sr][sc + 8] = k1;
        *(float4*)&Vs[buf][sr][sc]     = v0;
        *(float4*)&Vs[buf][sr][sc + 8] = v1;
        __syncthreads();

        // prefetch next tile (latency hides under this tile's compute)
        if (t + 1 < 33) {
            const int t2 = t + 1;
            const size_t sk = (size_t)((t2 >= p0len) ? (t2 - p0len) : t2) << 6;
            k0 = *(const float4*)(Kp + (sk + sr) * 64 + sc);
            k1 = *(const float4*)(Kp + (sk + sr) * 64 + sc + 8);
            v0 = *(const float4*)(Vp + (size_t)sr * 2048 + sk + sc);
            v1 = *(const float4*)(Vp + (size_t)sr * 2048 + sk + sc + 8);
        }

        // phase transition: finish qtBig, reset state, stage phase-1 Q
        if (t == p0len) {
            epilogue(qtBig);
            f4_t z = {0.f, 0.f, 0.f, 0.f};
            #pragma unroll
            for (int j = 0; j < 4; ++j) oacc[j] = z;
            lacc = z;
            *(float4*)&QP[sr][sc]     = q1a;   // wave-private rows, no barrier
            *(float4*)&QP[sr][sc + 8] = q1b;
            aq[0] = *(const bf8_t*)&QP[w * 16 + l16][quad * 8];
            aq[1] = *(const bf8_t*)&QP[w * 16 + l16][32 + quad * 8];
        }

        const bool ph1 = (t >= p0len);
        const int  kt  = ph1 ? (t - p0len) : t;
        const int  qt  = ph1 ? qtSmall : qtBig;
        const bool diag = (kt == qt);

        // S = Q K^T  (this wave's 16 rows)
        f4_t sacc[4];
        {
            f4_t z = {0.f, 0.f, 0.f, 0.f};
            #pragma unroll
            for (int j = 0; j < 4; ++j) sacc[j] = z;
        }
        #pragma unroll
        for (int ks = 0; ks < 2; ++ks) {
            #pragma unroll
            for (int nb = 0; nb < 4; ++nb) {
                bf8_t bk = *(const bf8_t*)&Ks[buf][nb * 16 + l16][ks * 32 + quad * 8];
                sacc[nb] = __builtin_amdgcn_mfma_f32_16x16x32_bf16(aq[ks], bk, sacc[nb], 0, 0, 0);
            }
        }

        // fixed-max softmax: p = exp2(s*0.125*log2e - 14*log2e); trunc-round P
        #pragma unroll
        for (int r = 0; r < 4; ++r) {
            const int rloc = (w << 4) + (quad << 2) + r;
            #pragma unroll
            for (int nb = 0; nb < 4; ++nb) {
                float e = fmaf(sacc[nb][r], 0.18033688f, -20.197731f);
                if (diag && (nb * 16 + l16 > rloc)) e = -1e30f;   // causal
                union { float f; unsigned int u; } pv;
                pv.f = exp2f(e);
                QP[rloc][nb * 16 + l16] = (unsigned short)(pv.u >> 16);
            }
        }

        // O += P V ; l += P . 1   (P rows wave-private -> no barrier)
        #pragma unroll
        for (int ks = 0; ks < 2; ++ks) {
            bf8_t ap = *(const bf8_t*)&QP[(w << 4) + l16][ks * 32 + quad * 8];
            #pragma unroll
            for (int nb = 0; nb < 4; ++nb) {
                bf8_t bv = *(const bf8_t*)&Vs[buf][nb * 16 + l16][ks * 32 + quad * 8];
                oacc[nb] = __builtin_amdgcn_mfma_f32_16x16x32_bf16(ap, bv, oacc[nb], 0, 0, 0);
            }
            lacc = __builtin_amdgcn_mfma_f32_16x16x32_bf16(ap, bones, lacc, 0, 0, 0);
        }
    }

    epilogue(qtSmall);
}

extern "C" void kernel_launch(void* const* d_in, const int* in_sizes, int n_in,
                              void* d_out, int out_size, void* d_ws, size_t ws_size,
                              hipStream_t stream) {
    const float* x    = (const float*)d_in[0];   // [2,2048,1024]
    const float* Wqkv = (const float*)d_in[1];   // [3072,1024]
    const float* bqkv = (const float*)d_in[2];   // [3072]
    const float* Wd   = (const float*)d_in[3];   // [1024,1024]
    const float* bd   = (const float*)d_in[4];   // [1024]
    float* out = (float*)d_out;                  // [2,2048,1024] fp32

    char* ws = (char*)d_ws;
    unsigned short* xb    = (unsigned short*)(ws);              // 8 MB  [4096][1024] bf16
    unsigned short* wqkvb = (unsigned short*)(ws + 8388608);    // 6 MB  [3072][1024]
    unsigned short* wdb   = (unsigned short*)(ws + 14680064);   // 2 MB  [1024][1024]
    unsigned short* qb2   = (unsigned short*)(ws + 16777216);   // 8 MB  [32][2048][64]
    unsigned short* kb2   = (unsigned short*)(ws + 25165824);   // 8 MB  [32][2048][64]
    unsigned short* vtb   = (unsigned short*)(ws + 33554432);   // 8 MB  [32][64][2048]
    unsigned short* ao    = xb;  // reuse x's bf16 buffer after QKV GEMM: [4096][1024]

    cvt_kernel<<<8192, 256, 0, stream>>>(x, xb, Wqkv, wqkvb, Wd, wdb);

    // QKV: [4096,3072] = xb [4096,1024] @ wqkvb^T + bqkv, scattered to q/k/vT
    gemm_bt_kernel<0><<<dim3(24, 64), 256, 0, stream>>>(
        xb, wqkvb, bqkv, nullptr, qb2, kb2, vtb, 1024, 3072);

    // causal flash attention (pair-balanced, XCD-swizzled) -> ao [4096][1024] bf16
    attn_kernel<<<512, 256, 0, stream>>>(qb2, kb2, vtb, ao);

    // out = ao @ wdb^T + bd  (fp32 out)
    gemm_bt_kernel<1><<<dim3(8, 64), 256, 0, stream>>>(
        ao, wdb, bd, out, nullptr, nullptr, nullptr, 1024, 1024);
}

// Round 7
// 183.445 us; speedup vs baseline: 1.1068x; 1.1068x over previous
//
#include <hip/hip_runtime.h>
#include <hip/hip_bf16.h>
#include <cstdint>
#include <cstddef>

// ---- types ----
typedef __attribute__((ext_vector_type(8))) short bf8_t;   // 8 x bf16 (4 VGPRs) MFMA A/B frag
typedef __attribute__((ext_vector_type(4))) float f4_t;    // MFMA C/D frag

__device__ __forceinline__ unsigned short f2bf(float f) {
    union { float f; unsigned int u; } v; v.f = f;
    unsigned int u = v.u + 0x7FFFu + ((v.u >> 16) & 1u);   // RNE
    return (unsigned short)(u >> 16);
}

// async global->LDS, 16B per lane. LDS dest = wave-uniform base + lane*16.
__device__ __forceinline__ void gl_lds16(const void* g, void* l) {
    __builtin_amdgcn_global_load_lds(
        (const __attribute__((address_space(1))) unsigned int*)g,
        (__attribute__((address_space(3))) unsigned int*)l,
        16, 0, 0);
}

// ---- fused fp32 -> bf16 convert for x, Wqkv, Wd ----
__global__ void cvt_kernel(const float* __restrict__ x,    unsigned short* __restrict__ xb,
                           const float* __restrict__ wq,   unsigned short* __restrict__ wqb,
                           const float* __restrict__ wd,   unsigned short* __restrict__ wdb) {
    int i = blockIdx.x * blockDim.x + threadIdx.x;          // over float4s, total 2097152
    const float* src; unsigned short* dst; int off;
    if (i < 1048576)       { src = x;  dst = xb;  off = i; }
    else if (i < 1835008)  { src = wq; dst = wqb; off = i - 1048576; }
    else                   { src = wd; dst = wdb; off = i - 1835008; }
    float4 f = ((const float4*)src)[off];
    ushort4 o;
    o.x = f2bf(f.x); o.y = f2bf(f.y); o.z = f2bf(f.z); o.w = f2bf(f.w);
    ((ushort4*)dst)[off] = o;
}

// ---- GEMM: C[M][N] = A[M][K] * W[N][K]^T + bias.  TM x 128, BK=64 ----
// Staging: one gl_lds16 = 64 lanes x 16 B = 8 rows x 64 bf16 cols. The LDS dest
// is pinned to base+lane*16, so we XOR-swizzle the GLOBAL source col-block per
// lane: lane (r=l>>3, c=l&7) loads col-block c^r. Fragment reads then find
// col-block cbi at position cbi^(row&7) -> ds_read_b128 banks tile all 32,
// 2 lanes/bank (free, m136). BK=64 halves barrier count vs BK=32.
// MODE 0: qkv epilogue -> scatter bf16 into q[b,h,s,64], k[b,h,s,64], vT[b,h,64,s]
// MODE 1: proj epilogue -> fp32 out[row*Nn + col]
template<int MODE, int TM>
__global__ __launch_bounds__(256, 2) void gemm_bt_kernel(
    const unsigned short* __restrict__ A,
    const unsigned short* __restrict__ W,
    const float* __restrict__ bias,
    float* __restrict__ outf,
    unsigned short* __restrict__ qb,
    unsigned short* __restrict__ kb,
    unsigned short* __restrict__ vtb,
    int K, int Nn)
{
    constexpr int HM = TM / 2;       // wave m-extent
    constexpr int MB = HM / 16;      // m-tiles per wave
    constexpr int AI = TM / 32;      // A staging instrs per wave

    __shared__ unsigned short As[TM][64];
    __shared__ unsigned short Bs[128][64];

    const int tid  = threadIdx.x;
    const int lane = tid & 63;
    const int w    = tid >> 6;      // wave 0..3
    const int wm   = w & 1;         // m-half
    const int wn   = w >> 1;        // n-half (64 cols)
    const int quad = lane >> 4;
    const int l16  = lane & 15;
    const int m0   = blockIdx.y * TM;
    const int n0   = blockIdx.x * 128;

    // staging lane mapping (8 rows x 64 cols per instr), XOR-swizzled source
    const int lrow = lane >> 3;                  // 0..7
    const int lcol = ((lane & 7) ^ lrow) << 3;   // swizzled col-block * 8

    f4_t acc[MB][4];
    {
        f4_t z = {0.f, 0.f, 0.f, 0.f};
        #pragma unroll
        for (int i = 0; i < MB; ++i)
            #pragma unroll
            for (int j = 0; j < 4; ++j) acc[i][j] = z;
    }

    const unsigned short* Agp = A + (size_t)(m0 + w * (TM / 4) + lrow) * K + lcol;
    const unsigned short* Bgp = W + (size_t)(n0 + w * 32 + lrow) * K + lcol;
    unsigned short* lAp = &As[w * (TM / 4)][0];
    unsigned short* lBp = &Bs[w * 32][0];

    for (int kk = 0; kk < K; kk += 64) {
        __syncthreads();                       // all waves done reading LDS
        #pragma unroll
        for (int i = 0; i < AI; ++i)
            gl_lds16(Agp + (size_t)(i * 8) * K + kk, lAp + i * 8 * 64);
        #pragma unroll
        for (int i = 0; i < 4; ++i)
            gl_lds16(Bgp + (size_t)(i * 8) * K + kk, lBp + i * 8 * 64);
        __syncthreads();                       // drains vmcnt, data visible

        const int sw = l16 & 7;
        #pragma unroll
        for (int ks = 0; ks < 2; ++ks) {
            bf8_t af[MB], bfr[4];
            #pragma unroll
            for (int mb = 0; mb < MB; ++mb)
                af[mb] = *(const bf8_t*)&As[wm * HM + mb * 16 + l16][(((ks << 2) | quad) ^ sw) << 3];
            #pragma unroll
            for (int nb = 0; nb < 4; ++nb)
                bfr[nb] = *(const bf8_t*)&Bs[wn * 64 + nb * 16 + l16][(((ks << 2) | quad) ^ sw) << 3];
            #pragma unroll
            for (int mb = 0; mb < MB; ++mb)
                #pragma unroll
                for (int nb = 0; nb < 4; ++nb)
                    acc[mb][nb] = __builtin_amdgcn_mfma_f32_16x16x32_bf16(af[mb], bfr[nb], acc[mb][nb], 0, 0, 0);
        }
    }

    #pragma unroll
    for (int nb = 0; nb < 4; ++nb) {
        const int col = n0 + wn * 64 + nb * 16 + l16;
        const float bc = bias[col];
        const int which  = col >> 10;
        const int within = col & 1023;
        const int head   = within >> 6;
        const int hdi    = within & 63;
        #pragma unroll
        for (int mb = 0; mb < MB; ++mb) {
            #pragma unroll
            for (int r = 0; r < 4; ++r) {
                const int row = m0 + wm * HM + mb * 16 + quad * 4 + r;
                const float v = acc[mb][nb][r] + bc;
                if (MODE == 0) {
                    const int b  = row >> 11;       // s = 2048
                    const int sq = row & 2047;
                    const int bh = b * 16 + head;
                    const unsigned short bv = f2bf(v);
                    if (which == 0)      qb [((size_t)bh * 2048 + sq) * 64 + hdi] = bv;
                    else if (which == 1) kb [((size_t)bh * 2048 + sq) * 64 + hdi] = bv;
                    else                 vtb[((size_t)bh * 64 + hdi) * 2048 + sq] = bv;
                } else {
                    outf[(size_t)row * Nn + col] = v;
                }
            }
        }
    }
}

// ---- flash attention, causal. Pair-balanced, XCD-swizzled.
// 1-D grid 512: bh = (bx&7)*4 + ((bx>>3)&3) -> each XCD owns 4 bh's (2 MB K/V < 4 MB L2).
// Double-buffered K/V LDS, ONE barrier/tile. Fixed-max softmax (M=14).
__global__ __launch_bounds__(256, 2) void attn_kernel(
    const unsigned short* __restrict__ qg,   // [bh][2048][64]
    const unsigned short* __restrict__ kg,   // [bh][2048][64]
    const unsigned short* __restrict__ vg,   // [bh][64][2048]  (V^T)
    unsigned short* __restrict__ ao)         // [b][sq][head*64+hd] = [4096][1024]
{
    __shared__ unsigned short QP[64][72];       // Q stage -> P (wave-private rows)
    __shared__ unsigned short Ks[2][64][72];
    __shared__ unsigned short Vs[2][64][72];    // [d][sk]

    const int tid  = threadIdx.x;
    const int lane = tid & 63;
    const int w    = tid >> 6;
    const int quad = lane >> 4;
    const int l16  = lane & 15;
    const int bx   = blockIdx.x;            // 0..511
    const int bh   = ((bx & 7) << 2) + ((bx >> 3) & 3);   // XCD-affine bh
    const int jj   = bx >> 5;               // 0..15 pair index
    const int qtBig   = 31 - jj;
    const int qtSmall = jj;
    const int b    = bh >> 4;
    const int head = bh & 15;

    const unsigned short* Qp = qg + (size_t)bh * 2048 * 64;
    const unsigned short* Kp = kg + (size_t)bh * 2048 * 64;
    const unsigned short* Vp = vg + (size_t)bh * 64 * 2048;

    const int sr = tid >> 2;            // 0..63 staging row (wave w -> rows 16w..16w+15)
    const int sc = (tid & 3) << 4;      // 0,16,32,48 shorts

    // prefetch both Q tiles into registers
    float4 q0a = *(const float4*)(Qp + (size_t)(qtBig * 64 + sr) * 64 + sc);
    float4 q0b = *(const float4*)(Qp + (size_t)(qtBig * 64 + sr) * 64 + sc + 8);
    float4 q1a = *(const float4*)(Qp + (size_t)(qtSmall * 64 + sr) * 64 + sc);
    float4 q1b = *(const float4*)(Qp + (size_t)(qtSmall * 64 + sr) * 64 + sc + 8);

    // prefetch K/V tile 0
    float4 k0 = *(const float4*)(Kp + (size_t)sr * 64 + sc);
    float4 k1 = *(const float4*)(Kp + (size_t)sr * 64 + sc + 8);
    float4 v0 = *(const float4*)(Vp + (size_t)sr * 2048 + sc);
    float4 v1 = *(const float4*)(Vp + (size_t)sr * 2048 + sc + 8);

    // stage phase-0 Q; frag rows are wave-private -> no barrier
    *(float4*)&QP[sr][sc]     = q0a;
    *(float4*)&QP[sr][sc + 8] = q0b;
    bf8_t aq[2];
    aq[0] = *(const bf8_t*)&QP[w * 16 + l16][quad * 8];
    aq[1] = *(const bf8_t*)&QP[w * 16 + l16][32 + quad * 8];

    // ones B-fragment: column n=0 all 1.0 -> MFMA row-sum of P
    bf8_t bones;
    {
        const short one = (l16 == 0) ? (short)0x3F80 : (short)0;
        #pragma unroll
        for (int j = 0; j < 8; ++j) bones[j] = one;
    }

    f4_t oacc[4];
    f4_t lacc;
    {
        f4_t z = {0.f, 0.f, 0.f, 0.f};
        #pragma unroll
        for (int j = 0; j < 4; ++j) oacc[j] = z;
        lacc = z;
    }

    auto epilogue = [&](int qt) {
        #pragma unroll
        for (int r = 0; r < 4; ++r) {
            const float lsum = __shfl(lacc[r], lane & 48);   // col 0 of quad
            const float rl = 1.f / lsum;
            const int sq = qt * 64 + (w << 4) + (quad << 2) + r;
            #pragma unroll
            for (int nb = 0; nb < 4; ++nb) {
                const int dcol = head * 64 + nb * 16 + l16;
                ao[((size_t)(b * 2048 + sq)) * 1024 + dcol] = f2bf(oacc[nb][r] * rl);
            }
        }
    };

    const int p0len = 32 - jj;     // tiles in phase 0 (qtBig+1)

    for (int t = 0; t < 33; ++t) {
        const int buf = t & 1;
        // stage K/V from prefetch regs into buf; readers of this buf were at
        // tile t-2 and have passed barrier t-1 -> safe with ONE barrier/tile
        *(float4*)&Ks[buf][sr][sc]     = k0;
        *(float4*)&Ks[buf][sr][sc + 8] = k1;
        *(float4*)&Vs[buf][sr][sc]     = v0;
        *(float4*)&Vs[buf][sr][sc + 8] = v1;
        __syncthreads();

        // prefetch next tile (latency hides under this tile's compute)
        if (t + 1 < 33) {
            const int t2 = t + 1;
            const size_t sk = (size_t)((t2 >= p0len) ? (t2 - p0len) : t2) << 6;
            k0 = *(const float4*)(Kp + (sk + sr) * 64 + sc);
            k1 = *(const float4*)(Kp + (sk + sr) * 64 + sc + 8);
            v0 = *(const float4*)(Vp + (size_t)sr * 2048 + sk + sc);
            v1 = *(const float4*)(Vp + (size_t)sr * 2048 + sk + sc + 8);
        }

        // phase transition: finish qtBig, reset state, stage phase-1 Q
        if (t == p0len) {
            epilogue(qtBig);
            f4_t z = {0.f, 0.f, 0.f, 0.f};
            #pragma unroll
            for (int j = 0; j < 4; ++j) oacc[j] = z;
            lacc = z;
            *(float4*)&QP[sr][sc]     = q1a;   // wave-private rows, no barrier
            *(float4*)&QP[sr][sc + 8] = q1b;
            aq[0] = *(const bf8_t*)&QP[w * 16 + l16][quad * 8];
            aq[1] = *(const bf8_t*)&QP[w * 16 + l16][32 + quad * 8];
        }

        const bool ph1 = (t >= p0len);
        const int  kt  = ph1 ? (t - p0len) : t;
        const int  qt  = ph1 ? qtSmall : qtBig;
        const bool diag = (kt == qt);

        // S = Q K^T  (this wave's 16 rows)
        f4_t sacc[4];
        {
            f4_t z = {0.f, 0.f, 0.f, 0.f};
            #pragma unroll
            for (int j = 0; j < 4; ++j) sacc[j] = z;
        }
        #pragma unroll
        for (int ks = 0; ks < 2; ++ks) {
            #pragma unroll
            for (int nb = 0; nb < 4; ++nb) {
                bf8_t bk = *(const bf8_t*)&Ks[buf][nb * 16 + l16][ks * 32 + quad * 8];
                sacc[nb] = __builtin_amdgcn_mfma_f32_16x16x32_bf16(aq[ks], bk, sacc[nb], 0, 0, 0);
            }
        }

        // fixed-max softmax: p = exp2(s*0.125*log2e - 14*log2e); trunc-round P
        #pragma unroll
        for (int r = 0; r < 4; ++r) {
            const int rloc = (w << 4) + (quad << 2) + r;
            #pragma unroll
            for (int nb = 0; nb < 4; ++nb) {
                float e = fmaf(sacc[nb][r], 0.18033688f, -20.197731f);
                if (diag && (nb * 16 + l16 > rloc)) e = -1e30f;   // causal
                union { float f; unsigned int u; } pv;
                pv.f = exp2f(e);
                QP[rloc][nb * 16 + l16] = (unsigned short)(pv.u >> 16);
            }
        }

        // O += P V ; l += P . 1   (P rows wave-private -> no barrier)
        #pragma unroll
        for (int ks = 0; ks < 2; ++ks) {
            bf8_t ap = *(const bf8_t*)&QP[(w << 4) + l16][ks * 32 + quad * 8];
            #pragma unroll
            for (int nb = 0; nb < 4; ++nb) {
                bf8_t bv = *(const bf8_t*)&Vs[buf][nb * 16 + l16][ks * 32 + quad * 8];
                oacc[nb] = __builtin_amdgcn_mfma_f32_16x16x32_bf16(ap, bv, oacc[nb], 0, 0, 0);
            }
            lacc = __builtin_amdgcn_mfma_f32_16x16x32_bf16(ap, bones, lacc, 0, 0, 0);
        }
    }

    epilogue(qtSmall);
}

extern "C" void kernel_launch(void* const* d_in, const int* in_sizes, int n_in,
                              void* d_out, int out_size, void* d_ws, size_t ws_size,
                              hipStream_t stream) {
    const float* x    = (const float*)d_in[0];   // [2,2048,1024]
    const float* Wqkv = (const float*)d_in[1];   // [3072,1024]
    const float* bqkv = (const float*)d_in[2];   // [3072]
    const float* Wd   = (const float*)d_in[3];   // [1024,1024]
    const float* bd   = (const float*)d_in[4];   // [1024]
    float* out = (float*)d_out;                  // [2,2048,1024] fp32

    char* ws = (char*)d_ws;
    unsigned short* xb    = (unsigned short*)(ws);              // 8 MB  [4096][1024] bf16
    unsigned short* wqkvb = (unsigned short*)(ws + 8388608);    // 6 MB  [3072][1024]
    unsigned short* wdb   = (unsigned short*)(ws + 14680064);   // 2 MB  [1024][1024]
    unsigned short* qb2   = (unsigned short*)(ws + 16777216);   // 8 MB  [32][2048][64]
    unsigned short* kb2   = (unsigned short*)(ws + 25165824);   // 8 MB  [32][2048][64]
    unsigned short* vtb   = (unsigned short*)(ws + 33554432);   // 8 MB  [32][64][2048]
    unsigned short* ao    = xb;  // reuse x's bf16 buffer after QKV GEMM: [4096][1024]

    cvt_kernel<<<8192, 256, 0, stream>>>(x, xb, Wqkv, wqkvb, Wd, wdb);

    // QKV: [4096,3072] = xb [4096,1024] @ wqkvb^T + bqkv, scattered to q/k/vT
    gemm_bt_kernel<0, 128><<<dim3(24, 32), 256, 0, stream>>>(
        xb, wqkvb, bqkv, nullptr, qb2, kb2, vtb, 1024, 3072);

    // causal flash attention (pair-balanced, XCD-swizzled) -> ao [4096][1024] bf16
    attn_kernel<<<512, 256, 0, stream>>>(qb2, kb2, vtb, ao);

    // out = ao @ wdb^T + bd  (fp32 out)
    gemm_bt_kernel<1, 64><<<dim3(8, 64), 256, 0, stream>>>(
        ao, wdb, bd, out, nullptr, nullptr, nullptr, 1024, 1024);
}

// Round 8
// 180.721 us; speedup vs baseline: 1.1235x; 1.0151x over previous
//
#include <hip/hip_runtime.h>
#include <hip/hip_bf16.h>
#include <cstdint>
#include <cstddef>

// ---- types ----
typedef __attribute__((ext_vector_type(8))) short bf8_t;   // 8 x bf16 (4 VGPRs) MFMA A/B frag
typedef __attribute__((ext_vector_type(4))) float f4_t;    // MFMA C/D frag

__device__ __forceinline__ unsigned short f2bf(float f) {
    union { float f; unsigned int u; } v; v.f = f;
    unsigned int u = v.u + 0x7FFFu + ((v.u >> 16) & 1u);   // RNE
    return (unsigned short)(u >> 16);
}
__device__ __forceinline__ float bf2f(unsigned short s) {
    union { unsigned int u; float f; } v; v.u = ((unsigned int)s) << 16;
    return v.f;
}

// async global->LDS, 16B per lane. LDS dest = wave-uniform base + lane*16.
__device__ __forceinline__ void gl_lds16(const void* g, void* l) {
    __builtin_amdgcn_global_load_lds(
        (const __attribute__((address_space(1))) unsigned int*)g,
        (__attribute__((address_space(3))) unsigned int*)l,
        16, 0, 0);
}

// ---- fused fp32 -> bf16 convert for x, Wqkv, Wd ----
__global__ void cvt_kernel(const float* __restrict__ x,    unsigned short* __restrict__ xb,
                           const float* __restrict__ wq,   unsigned short* __restrict__ wqb,
                           const float* __restrict__ wd,   unsigned short* __restrict__ wdb) {
    int i = blockIdx.x * blockDim.x + threadIdx.x;          // over float4s, total 2097152
    const float* src; unsigned short* dst; int off;
    if (i < 1048576)       { src = x;  dst = xb;  off = i; }
    else if (i < 1835008)  { src = wq; dst = wqb; off = i - 1048576; }
    else                   { src = wd; dst = wdb; off = i - 1835008; }
    float4 f = ((const float4*)src)[off];
    ushort4 o;
    o.x = f2bf(f.x); o.y = f2bf(f.y); o.z = f2bf(f.z); o.w = f2bf(f.w);
    ((ushort4*)dst)[off] = o;
}

// ---- GEMM: C[M][N] = A[M][K] * W[N][K]^T + bias.  TM x 128, BK=64 ----
// XOR-swizzled gl_lds16 staging (see R7 notes).
template<int MODE, int TM>
__global__ __launch_bounds__(256, 2) void gemm_bt_kernel(
    const unsigned short* __restrict__ A,
    const unsigned short* __restrict__ W,
    const float* __restrict__ bias,
    float* __restrict__ outf,
    unsigned short* __restrict__ qb,
    unsigned short* __restrict__ kb,
    unsigned short* __restrict__ vtb,
    int K, int Nn)
{
    constexpr int HM = TM / 2;
    constexpr int MB = HM / 16;
    constexpr int AI = TM / 32;

    __shared__ unsigned short As[TM][64];
    __shared__ unsigned short Bs[128][64];

    const int tid  = threadIdx.x;
    const int lane = tid & 63;
    const int w    = tid >> 6;
    const int wm   = w & 1;
    const int wn   = w >> 1;
    const int quad = lane >> 4;
    const int l16  = lane & 15;
    const int m0   = blockIdx.y * TM;
    const int n0   = blockIdx.x * 128;

    const int lrow = lane >> 3;                  // 0..7
    const int lcol = ((lane & 7) ^ lrow) << 3;   // swizzled col-block * 8

    f4_t acc[MB][4];
    {
        f4_t z = {0.f, 0.f, 0.f, 0.f};
        #pragma unroll
        for (int i = 0; i < MB; ++i)
            #pragma unroll
            for (int j = 0; j < 4; ++j) acc[i][j] = z;
    }

    const unsigned short* Agp = A + (size_t)(m0 + w * (TM / 4) + lrow) * K + lcol;
    const unsigned short* Bgp = W + (size_t)(n0 + w * 32 + lrow) * K + lcol;
    unsigned short* lAp = &As[w * (TM / 4)][0];
    unsigned short* lBp = &Bs[w * 32][0];

    for (int kk = 0; kk < K; kk += 64) {
        __syncthreads();
        #pragma unroll
        for (int i = 0; i < AI; ++i)
            gl_lds16(Agp + (size_t)(i * 8) * K + kk, lAp + i * 8 * 64);
        #pragma unroll
        for (int i = 0; i < 4; ++i)
            gl_lds16(Bgp + (size_t)(i * 8) * K + kk, lBp + i * 8 * 64);
        __syncthreads();

        const int sw = l16 & 7;
        #pragma unroll
        for (int ks = 0; ks < 2; ++ks) {
            bf8_t af[MB], bfr[4];
            #pragma unroll
            for (int mb = 0; mb < MB; ++mb)
                af[mb] = *(const bf8_t*)&As[wm * HM + mb * 16 + l16][(((ks << 2) | quad) ^ sw) << 3];
            #pragma unroll
            for (int nb = 0; nb < 4; ++nb)
                bfr[nb] = *(const bf8_t*)&Bs[wn * 64 + nb * 16 + l16][(((ks << 2) | quad) ^ sw) << 3];
            #pragma unroll
            for (int mb = 0; mb < MB; ++mb)
                #pragma unroll
                for (int nb = 0; nb < 4; ++nb)
                    acc[mb][nb] = __builtin_amdgcn_mfma_f32_16x16x32_bf16(af[mb], bfr[nb], acc[mb][nb], 0, 0, 0);
        }
    }

    #pragma unroll
    for (int nb = 0; nb < 4; ++nb) {
        const int col = n0 + wn * 64 + nb * 16 + l16;
        const float bc = bias[col];
        const int which  = col >> 10;
        const int within = col & 1023;
        const int head   = within >> 6;
        const int hdi    = within & 63;
        #pragma unroll
        for (int mb = 0; mb < MB; ++mb) {
            #pragma unroll
            for (int r = 0; r < 4; ++r) {
                const int row = m0 + wm * HM + mb * 16 + quad * 4 + r;
                const float v = acc[mb][nb][r] + bc;
                if (MODE == 0) {
                    const int b  = row >> 11;       // s = 2048
                    const int sq = row & 2047;
                    const int bh = b * 16 + head;
                    const unsigned short bv = f2bf(v);
                    if (which == 0)      qb [((size_t)bh * 2048 + sq) * 64 + hdi] = bv;
                    else if (which == 1) kb [((size_t)bh * 2048 + sq) * 64 + hdi] = bv;
                    else                 vtb[((size_t)bh * 64 + hdi) * 2048 + sq] = bv;
                } else {
                    outf[(size_t)row * Nn + col] = v;
                }
            }
        }
    }
}

// ---- flash attention, causal, split-K halves. ----
// 1024 blocks: bx = [jj:4][h:1][b2:2][xcd:3]; bh=(xcd<<2)|b2 (4 bh per XCD, L2-warm).
// Pair (qtBig=31-jj, qtSmall=jj) = 33 tiles; h0 takes seq positions [0,17),
// h1 takes [17,33). Fixed-max softmax => partials (O,l) simply ADD across
// halves: qtBig merged by merge_kernel, qtSmall written direct by h1.
// LDS = 5 x 8 KB (K dbuf, V dbuf, P) = exactly 40 KB -> 4 blocks/CU.
// K/V staged by gl_lds16 with XOR col-block swizzle; Q frags direct from global.
__global__ __launch_bounds__(256, 4) void attn_kernel(
    const unsigned short* __restrict__ qg,   // [bh][2048][64]
    const unsigned short* __restrict__ kg,   // [bh][2048][64]
    const unsigned short* __restrict__ vg,   // [bh][64][2048]  (V^T)
    unsigned short* __restrict__ ao,         // [b][sq][head*64+hd] = [4096][1024]
    unsigned short* __restrict__ pO,         // [2][512][64*64] bf16 partial O
    float* __restrict__ pL)                  // [2][512][64]    fp32 partial l
{
    __shared__ unsigned short Ks[2][4096];
    __shared__ unsigned short Vs[2][4096];
    __shared__ unsigned short Ps[4096];

    const int tid  = threadIdx.x;
    const int lane = tid & 63;
    const int w    = tid >> 6;
    const int quad = lane >> 4;
    const int l16  = lane & 15;
    const int bx   = blockIdx.x;                          // 0..1023
    const int bh   = ((bx & 7) << 2) | ((bx >> 3) & 3);   // XCD-affine bh
    const int h    = (bx >> 5) & 1;
    const int jj   = bx >> 6;                             // 0..15
    const int qtBig   = 31 - jj;
    const int qtSmall = jj;
    const int b    = bh >> 4;
    const int head = bh & 15;
    const int p0len = 32 - jj;             // tiles in qtBig phase
    const int t0 = h ? 17 : 0;
    const int t1 = h ? 33 : 17;

    const unsigned short* Qp = qg + (size_t)bh * 2048 * 64;
    const unsigned short* Kp = kg + (size_t)bh * 2048 * 64;
    const unsigned short* Vp = vg + (size_t)bh * 64 * 2048;

    // staging geometry: one gl_lds16 = 8 rows x 64 cols; XOR-swizzled source
    const int srow = lane >> 3;
    const int scol = ((lane & 7) ^ srow) << 3;
    const unsigned short* kga = Kp + (size_t)(w * 16 + srow) * 64 + scol;
    const unsigned short* vga = Vp + (size_t)(w * 16 + srow) * 2048 + scol;
    const int sw = l16 & 7;                // frag-read swizzle key (row&7)

    auto stageKV = [&](int kt, int buf) {
        const int sk0 = kt << 6;
        gl_lds16(kga + (size_t)sk0 * 64,       &Ks[buf][w * 16 * 64]);
        gl_lds16(kga + (size_t)sk0 * 64 + 512, &Ks[buf][(w * 16 + 8) * 64]);
        gl_lds16(vga + sk0,                    &Vs[buf][w * 16 * 64]);
        gl_lds16(vga + sk0 + 8 * 2048,         &Vs[buf][(w * 16 + 8) * 64]);
    };

    // ones B-fragment: column n=0 all 1.0 -> MFMA row-sum of P
    bf8_t bones;
    {
        const short one = (l16 == 0) ? (short)0x3F80 : (short)0;
        #pragma unroll
        for (int j = 0; j < 8; ++j) bones[j] = one;
    }

    f4_t oacc[4];
    f4_t lacc;
    {
        f4_t z = {0.f, 0.f, 0.f, 0.f};
        #pragma unroll
        for (int j = 0; j < 4; ++j) oacc[j] = z;
        lacc = z;
    }

    // Q A-fragments straight from global (L2-hot), per phase
    bf8_t aq[2];
    {
        const int qt_init = (t0 >= p0len) ? qtSmall : qtBig;
        const size_t qrow = (size_t)(qt_init * 64 + w * 16 + l16) * 64;
        aq[0] = *(const bf8_t*)(Qp + qrow + quad * 8);
        aq[1] = *(const bf8_t*)(Qp + qrow + 32 + quad * 8);
    }

    auto flushPartial = [&]() {
        const int tb = (h << 9) + (bh << 4) + jj;
        unsigned short* po = pO + (size_t)tb * 4096;
        #pragma unroll
        for (int r = 0; r < 4; ++r) {
            const int row = w * 16 + quad * 4 + r;
            #pragma unroll
            for (int nb = 0; nb < 4; ++nb)
                po[row * 64 + nb * 16 + l16] = f2bf(oacc[nb][r]);
            if (l16 == 0) pL[tb * 64 + row] = lacc[r];
        }
    };

    // pre-issue tile t0
    {
        const int kt0 = (t0 >= p0len) ? (t0 - p0len) : t0;
        stageKV(kt0, t0 & 1);
    }

    for (int t = t0; t < t1; ++t) {
        const int buf = t & 1;
        __syncthreads();                   // drains vmcnt: tile t visible

        if (t + 1 < t1) {
            const int t2 = t + 1;
            stageKV((t2 >= p0len) ? (t2 - p0len) : t2, t2 & 1);
        }

        // phase transition (h=1 only): flush qtBig partial, reset, re-load aq
        if (t == p0len) {
            flushPartial();
            f4_t z = {0.f, 0.f, 0.f, 0.f};
            #pragma unroll
            for (int j = 0; j < 4; ++j) oacc[j] = z;
            lacc = z;
            const size_t qrow = (size_t)(qtSmall * 64 + w * 16 + l16) * 64;
            aq[0] = *(const bf8_t*)(Qp + qrow + quad * 8);
            aq[1] = *(const bf8_t*)(Qp + qrow + 32 + quad * 8);
        }

        const bool ph1 = (t >= p0len);
        const int  kt  = ph1 ? (t - p0len) : t;
        const int  qtc = ph1 ? qtSmall : qtBig;
        const bool diag = (kt == qtc);

        // S = Q K^T (this wave's 16 rows)
        f4_t sacc[4];
        {
            f4_t z = {0.f, 0.f, 0.f, 0.f};
            #pragma unroll
            for (int j = 0; j < 4; ++j) sacc[j] = z;
        }
        #pragma unroll
        for (int ks = 0; ks < 2; ++ks) {
            #pragma unroll
            for (int nb = 0; nb < 4; ++nb) {
                bf8_t bk = *(const bf8_t*)&Ks[buf][(nb * 16 + l16) * 64 + (((((ks << 2) | quad)) ^ sw) << 3)];
                sacc[nb] = __builtin_amdgcn_mfma_f32_16x16x32_bf16(aq[ks], bk, sacc[nb], 0, 0, 0);
            }
        }

        // fixed-max softmax: p = exp2(s*0.125*log2e - 14*log2e); trunc-round P.
        // P stored XOR-swizzled: block' = block ^ (row&7)
        #pragma unroll
        for (int r = 0; r < 4; ++r) {
            const int rloc = (w << 4) + (quad << 2) + r;
            const int rk = rloc & 7;
            #pragma unroll
            for (int nb = 0; nb < 4; ++nb) {
                float e = fmaf(sacc[nb][r], 0.18033688f, -20.197731f);
                if (diag && (nb * 16 + l16 > rloc)) e = -1e30f;   // causal
                union { float f; unsigned int u; } pv;
                pv.f = exp2f(e);
                Ps[rloc * 64 + ((((nb << 1) | (l16 >> 3)) ^ rk) << 3) + (l16 & 7)] =
                    (unsigned short)(pv.u >> 16);
            }
        }

        // O += P V ; l += P . 1
        #pragma unroll
        for (int ks = 0; ks < 2; ++ks) {
            bf8_t ap = *(const bf8_t*)&Ps[(w * 16 + l16) * 64 + ((((ks << 2) | quad) ^ sw) << 3)];
            #pragma unroll
            for (int nb = 0; nb < 4; ++nb) {
                bf8_t bv = *(const bf8_t*)&Vs[buf][(nb * 16 + l16) * 64 + ((((ks << 2) | quad) ^ sw) << 3)];
                oacc[nb] = __builtin_amdgcn_mfma_f32_16x16x32_bf16(ap, bv, oacc[nb], 0, 0, 0);
            }
            lacc = __builtin_amdgcn_mfma_f32_16x16x32_bf16(ap, bones, lacc, 0, 0, 0);
        }
    }

    if (!h) {
        flushPartial();                    // h0: qtBig partial
    } else {
        // h1: qtSmall complete -> normalize and write direct
        #pragma unroll
        for (int r = 0; r < 4; ++r) {
            const float lsum = __shfl(lacc[r], lane & 48);
            const float rl = 1.f / lsum;
            const int sq = qtSmall * 64 + (w << 4) + (quad << 2) + r;
            #pragma unroll
            for (int nb = 0; nb < 4; ++nb) {
                const int dcol = head * 64 + nb * 16 + l16;
                ao[((size_t)(b * 2048 + sq)) * 1024 + dcol] = f2bf(oacc[nb][r] * rl);
            }
        }
    }
}

// ---- merge the two qtBig partials: O = (O0+O1)/(l0+l1) -> ao ----
__global__ void merge_kernel(const unsigned short* __restrict__ pO,
                             const float* __restrict__ pL,
                             unsigned short* __restrict__ ao) {
    const int blk  = blockIdx.x;        // 0..511 = bh*16 + jj
    const int bh   = blk >> 4;
    const int jj   = blk & 15;
    const int b    = bh >> 4;
    const int head = bh & 15;
    const int qt   = 31 - jj;
    const int row  = threadIdx.x >> 2;          // 0..63
    const int c0   = (threadIdx.x & 3) << 4;    // 0,16,32,48

    const float l = pL[blk * 64 + row] + pL[(512 + blk) * 64 + row];
    const float rl = 1.f / l;
    const unsigned short* p0 = pO + (size_t)blk * 4096 + row * 64 + c0;
    const unsigned short* p1 = pO + (size_t)(512 + blk) * 4096 + row * 64 + c0;
    unsigned short* dst = ao + ((size_t)(b * 2048 + qt * 64 + row)) * 1024 + head * 64 + c0;
    #pragma unroll
    for (int j = 0; j < 16; ++j)
        dst[j] = f2bf((bf2f(p0[j]) + bf2f(p1[j])) * rl);
}

extern "C" void kernel_launch(void* const* d_in, const int* in_sizes, int n_in,
                              void* d_out, int out_size, void* d_ws, size_t ws_size,
                              hipStream_t stream) {
    const float* x    = (const float*)d_in[0];   // [2,2048,1024]
    const float* Wqkv = (const float*)d_in[1];   // [3072,1024]
    const float* bqkv = (const float*)d_in[2];   // [3072]
    const float* Wd   = (const float*)d_in[3];   // [1024,1024]
    const float* bd   = (const float*)d_in[4];   // [1024]
    float* out = (float*)d_out;                  // [2,2048,1024] fp32

    char* ws = (char*)d_ws;
    unsigned short* xb    = (unsigned short*)(ws);              // 8 MB  [4096][1024] bf16
    unsigned short* wqkvb = (unsigned short*)(ws + 8388608);    // 6 MB  [3072][1024]
    unsigned short* wdb   = (unsigned short*)(ws + 14680064);   // 2 MB  [1024][1024]
    unsigned short* qb2   = (unsigned short*)(ws + 16777216);   // 8 MB  [32][2048][64]
    unsigned short* kb2   = (unsigned short*)(ws + 25165824);   // 8 MB  [32][2048][64]
    unsigned short* vtb   = (unsigned short*)(ws + 33554432);   // 8 MB  [32][64][2048]
    unsigned short* pO    = (unsigned short*)(ws + 41943040);   // 8 MB  [2][512][4096] bf16
    float*          pL    = (float*)(ws + 50331648);            // 256KB [2][512][64] fp32
    unsigned short* ao    = xb;  // reuse x's bf16 buffer after QKV GEMM: [4096][1024]

    cvt_kernel<<<8192, 256, 0, stream>>>(x, xb, Wqkv, wqkvb, Wd, wdb);

    // QKV: [4096,3072] = xb [4096,1024] @ wqkvb^T + bqkv, scattered to q/k/vT
    gemm_bt_kernel<0, 128><<<dim3(24, 32), 256, 0, stream>>>(
        xb, wqkvb, bqkv, nullptr, qb2, kb2, vtb, 1024, 3072);

    // causal flash attention (split-K halves, pair-balanced, XCD-swizzled)
    attn_kernel<<<1024, 256, 0, stream>>>(qb2, kb2, vtb, ao, pO, pL);

    // merge qtBig partials into ao
    merge_kernel<<<512, 256, 0, stream>>>(pO, pL, ao);

    // out = ao @ wdb^T + bd  (fp32 out)
    gemm_bt_kernel<1, 64><<<dim3(8, 64), 256, 0, stream>>>(
        ao, wdb, bd, out, nullptr, nullptr, nullptr, 1024, 1024);
}

// Round 9
// 178.093 us; speedup vs baseline: 1.1401x; 1.0148x over previous
//
#include <hip/hip_runtime.h>
#include <hip/hip_bf16.h>
#include <cstdint>
#include <cstddef>

// ---- types ----
typedef __attribute__((ext_vector_type(8))) short bf8_t;   // 8 x bf16 (4 VGPRs) MFMA A/B frag
typedef __attribute__((ext_vector_type(4))) float f4_t;    // MFMA C/D frag

__device__ __forceinline__ unsigned short f2bf(float f) {
    union { float f; unsigned int u; } v; v.f = f;
    unsigned int u = v.u + 0x7FFFu + ((v.u >> 16) & 1u);   // RNE
    return (unsigned short)(u >> 16);
}
__device__ __forceinline__ float bf2f(unsigned short s) {
    union { unsigned int u; float f; } v; v.u = ((unsigned int)s) << 16;
    return v.f;
}

// async global->LDS, 16B per lane. LDS dest = wave-uniform base + lane*16.
__device__ __forceinline__ void gl_lds16(const void* g, void* l) {
    __builtin_amdgcn_global_load_lds(
        (const __attribute__((address_space(1))) unsigned int*)g,
        (__attribute__((address_space(3))) unsigned int*)l,
        16, 0, 0);
}

// ---- fused fp32 -> bf16 convert for x, Wqkv, Wd ----
__global__ void cvt_kernel(const float* __restrict__ x,    unsigned short* __restrict__ xb,
                           const float* __restrict__ wq,   unsigned short* __restrict__ wqb,
                           const float* __restrict__ wd,   unsigned short* __restrict__ wdb) {
    int i = blockIdx.x * blockDim.x + threadIdx.x;          // over float4s, total 2097152
    const float* src; unsigned short* dst; int off;
    if (i < 1048576)       { src = x;  dst = xb;  off = i; }
    else if (i < 1835008)  { src = wq; dst = wqb; off = i - 1048576; }
    else                   { src = wd; dst = wdb; off = i - 1835008; }
    float4 f = ((const float4*)src)[off];
    ushort4 o;
    o.x = f2bf(f.x); o.y = f2bf(f.y); o.z = f2bf(f.z); o.w = f2bf(f.w);
    ((ushort4*)dst)[off] = o;
}

// ---- GEMM body: C[M][N] = A[M][K] * W[N][K]^T + bias.  TM x 128, BK=64 ----
// XOR-swizzled gl_lds16 staging. MODE 0: qkv epilogue (q/k direct scatter;
// pure-V blocks transposed through LDS for coalesced V^T stores).
// MODE 1: proj epilogue -> fp32 out.
template<int MODE, int TM>
__device__ __forceinline__ void gemm_body(
    const unsigned short* __restrict__ A,
    const unsigned short* __restrict__ W,
    const float* __restrict__ bias,
    float* __restrict__ outf,
    unsigned short* __restrict__ qb,
    unsigned short* __restrict__ kb,
    unsigned short* __restrict__ vtb,
    int K, int Nn)
{
    constexpr int HM = TM / 2;
    constexpr int MB = HM / 16;
    constexpr int AI = TM / 32;
    // staging needs (TM+128)*64 shorts; MODE 0 V-transpose needs 128*136
    constexpr int SSTG = (TM + 128) * 64;
    constexpr int SMEM = (MODE == 0 && SSTG < 128 * 136) ? 128 * 136 : SSTG;

    __shared__ unsigned short smem[SMEM];
    unsigned short* As = smem;              // [TM][64]
    unsigned short* Bs = smem + TM * 64;    // [128][64]

    const int tid  = threadIdx.x;
    const int lane = tid & 63;
    const int w    = tid >> 6;
    const int wm   = w & 1;
    const int wn   = w >> 1;
    const int quad = lane >> 4;
    const int l16  = lane & 15;
    const int m0   = blockIdx.y * TM;
    const int n0   = blockIdx.x * 128;

    const int lrow = lane >> 3;                  // 0..7
    const int lcol = ((lane & 7) ^ lrow) << 3;   // swizzled col-block * 8

    f4_t acc[MB][4];
    {
        f4_t z = {0.f, 0.f, 0.f, 0.f};
        #pragma unroll
        for (int i = 0; i < MB; ++i)
            #pragma unroll
            for (int j = 0; j < 4; ++j) acc[i][j] = z;
    }

    const unsigned short* Agp = A + (size_t)(m0 + w * (TM / 4) + lrow) * K + lcol;
    const unsigned short* Bgp = W + (size_t)(n0 + w * 32 + lrow) * K + lcol;
    unsigned short* lAp = &As[(w * (TM / 4)) * 64];
    unsigned short* lBp = &Bs[(w * 32) * 64];

    for (int kk = 0; kk < K; kk += 64) {
        __syncthreads();
        #pragma unroll
        for (int i = 0; i < AI; ++i)
            gl_lds16(Agp + (size_t)(i * 8) * K + kk, lAp + i * 8 * 64);
        #pragma unroll
        for (int i = 0; i < 4; ++i)
            gl_lds16(Bgp + (size_t)(i * 8) * K + kk, lBp + i * 8 * 64);
        __syncthreads();

        const int sw = l16 & 7;
        #pragma unroll
        for (int ks = 0; ks < 2; ++ks) {
            bf8_t af[MB], bfr[4];
            #pragma unroll
            for (int mb = 0; mb < MB; ++mb)
                af[mb] = *(const bf8_t*)&As[(wm * HM + mb * 16 + l16) * 64 + ((((ks << 2) | quad) ^ sw) << 3)];
            #pragma unroll
            for (int nb = 0; nb < 4; ++nb)
                bfr[nb] = *(const bf8_t*)&Bs[(wn * 64 + nb * 16 + l16) * 64 + ((((ks << 2) | quad) ^ sw) << 3)];
            #pragma unroll
            for (int mb = 0; mb < MB; ++mb)
                #pragma unroll
                for (int nb = 0; nb < 4; ++nb)
                    acc[mb][nb] = __builtin_amdgcn_mfma_f32_16x16x32_bf16(af[mb], bfr[nb], acc[mb][nb], 0, 0, 0);
        }
    }

    if (MODE == 0 && n0 >= 2048) {
        // pure-V block: transpose via LDS, store V^T coalesced (128-B runs)
        unsigned short* T = smem;            // [128 cols][136]
        __syncthreads();                     // main-loop LDS reads done
        #pragma unroll
        for (int nb = 0; nb < 4; ++nb) {
            const int colL = wn * 64 + nb * 16 + l16;
            const float bc = bias[n0 + colL];
            #pragma unroll
            for (int mb = 0; mb < MB; ++mb) {
                const int rowL = wm * HM + mb * 16 + quad * 4;
                uint2 p;
                p.x = (unsigned int)f2bf(acc[mb][nb][0] + bc) |
                      ((unsigned int)f2bf(acc[mb][nb][1] + bc) << 16);
                p.y = (unsigned int)f2bf(acc[mb][nb][2] + bc) |
                      ((unsigned int)f2bf(acc[mb][nb][3] + bc) << 16);
                *(uint2*)&T[colL * 136 + rowL] = p;
            }
        }
        __syncthreads();
        const int trow  = tid >> 1;              // hdi-local 0..127
        const int thalf = (tid & 1) << 6;        // sq half
        const int head  = ((n0 - 2048) >> 6) + (trow >> 6);
        const int hdi   = trow & 63;
        const int bh    = ((m0 >> 11) << 4) + head;
        const int sq0   = (m0 & 2047) + thalf;
        unsigned short* dst = vtb + ((size_t)bh * 64 + hdi) * 2048 + sq0;
        const unsigned short* srcT = &T[trow * 136 + thalf];
        #pragma unroll
        for (int j = 0; j < 8; ++j)
            *(float4*)(dst + j * 8) = *(const float4*)(srcT + j * 8);
        return;
    }

    #pragma unroll
    for (int nb = 0; nb < 4; ++nb) {
        const int col = n0 + wn * 64 + nb * 16 + l16;
        const float bc = bias[col];
        const int within = col & 1023;
        const int head   = within >> 6;
        const int hdi    = within & 63;
        const bool isQ   = (col < 1024);
        #pragma unroll
        for (int mb = 0; mb < MB; ++mb) {
            #pragma unroll
            for (int r = 0; r < 4; ++r) {
                const int row = m0 + wm * HM + mb * 16 + quad * 4 + r;
                const float v = acc[mb][nb][r] + bc;
                if (MODE == 0) {
                    const int b  = row >> 11;       // s = 2048
                    const int sq = row & 2047;
                    const int bh = b * 16 + head;
                    const unsigned short bv = f2bf(v);
                    if (isQ) qb[((size_t)bh * 2048 + sq) * 64 + hdi] = bv;
                    else     kb[((size_t)bh * 2048 + sq) * 64 + hdi] = bv;
                } else {
                    outf[(size_t)row * Nn + col] = v;
                }
            }
        }
    }
}

__global__ __launch_bounds__(256, 2) void qkv_gemm(
    const unsigned short* __restrict__ A, const unsigned short* __restrict__ W,
    const float* __restrict__ bias, unsigned short* __restrict__ qb,
    unsigned short* __restrict__ kb, unsigned short* __restrict__ vtb, int K, int Nn)
{
    gemm_body<0, 128>(A, W, bias, nullptr, qb, kb, vtb, K, Nn);
}

__global__ __launch_bounds__(256, 2) void proj_gemm(
    const unsigned short* __restrict__ A, const unsigned short* __restrict__ W,
    const float* __restrict__ bias, float* __restrict__ outf, int K, int Nn)
{
    gemm_body<1, 64>(A, W, bias, outf, nullptr, nullptr, nullptr, K, Nn);
}

// ---- flash attention, causal, split-K halves (see R8 notes). ----
__global__ __launch_bounds__(256, 4) void attn_kernel(
    const unsigned short* __restrict__ qg,   // [bh][2048][64]
    const unsigned short* __restrict__ kg,   // [bh][2048][64]
    const unsigned short* __restrict__ vg,   // [bh][64][2048]  (V^T)
    unsigned short* __restrict__ ao,         // [b][sq][head*64+hd] = [4096][1024]
    unsigned short* __restrict__ pO,         // [2][512][64*64] bf16 partial O
    float* __restrict__ pL)                  // [2][512][64]    fp32 partial l
{
    __shared__ unsigned short Ks[2][4096];
    __shared__ unsigned short Vs[2][4096];
    __shared__ unsigned short Ps[4096];

    const int tid  = threadIdx.x;
    const int lane = tid & 63;
    const int w    = tid >> 6;
    const int quad = lane >> 4;
    const int l16  = lane & 15;
    const int bx   = blockIdx.x;                          // 0..1023
    const int bh   = ((bx & 7) << 2) | ((bx >> 3) & 3);   // XCD-affine bh
    const int h    = (bx >> 5) & 1;
    const int jj   = bx >> 6;                             // 0..15
    const int qtBig   = 31 - jj;
    const int qtSmall = jj;
    const int b    = bh >> 4;
    const int head = bh & 15;
    const int p0len = 32 - jj;             // tiles in qtBig phase
    const int t0 = h ? 17 : 0;
    const int t1 = h ? 33 : 17;

    const unsigned short* Qp = qg + (size_t)bh * 2048 * 64;
    const unsigned short* Kp = kg + (size_t)bh * 2048 * 64;
    const unsigned short* Vp = vg + (size_t)bh * 64 * 2048;

    // staging geometry: one gl_lds16 = 8 rows x 64 cols; XOR-swizzled source
    const int srow = lane >> 3;
    const int scol = ((lane & 7) ^ srow) << 3;
    const unsigned short* kga = Kp + (size_t)(w * 16 + srow) * 64 + scol;
    const unsigned short* vga = Vp + (size_t)(w * 16 + srow) * 2048 + scol;
    const int sw = l16 & 7;                // frag-read swizzle key (row&7)

    auto stageKV = [&](int kt, int buf) {
        const int sk0 = kt << 6;
        gl_lds16(kga + (size_t)sk0 * 64,       &Ks[buf][w * 16 * 64]);
        gl_lds16(kga + (size_t)sk0 * 64 + 512, &Ks[buf][(w * 16 + 8) * 64]);
        gl_lds16(vga + sk0,                    &Vs[buf][w * 16 * 64]);
        gl_lds16(vga + sk0 + 8 * 2048,         &Vs[buf][(w * 16 + 8) * 64]);
    };

    // ones B-fragment: column n=0 all 1.0 -> MFMA row-sum of P
    bf8_t bones;
    {
        const short one = (l16 == 0) ? (short)0x3F80 : (short)0;
        #pragma unroll
        for (int j = 0; j < 8; ++j) bones[j] = one;
    }

    f4_t oacc[4];
    f4_t lacc;
    {
        f4_t z = {0.f, 0.f, 0.f, 0.f};
        #pragma unroll
        for (int j = 0; j < 4; ++j) oacc[j] = z;
        lacc = z;
    }

    // Q A-fragments straight from global (L2-hot), per phase
    bf8_t aq[2];
    {
        const int qt_init = (t0 >= p0len) ? qtSmall : qtBig;
        const size_t qrow = (size_t)(qt_init * 64 + w * 16 + l16) * 64;
        aq[0] = *(const bf8_t*)(Qp + qrow + quad * 8);
        aq[1] = *(const bf8_t*)(Qp + qrow + 32 + quad * 8);
    }

    auto flushPartial = [&]() {
        const int tb = (h << 9) + (bh << 4) + jj;
        unsigned short* po = pO + (size_t)tb * 4096;
        #pragma unroll
        for (int r = 0; r < 4; ++r) {
            const int row = w * 16 + quad * 4 + r;
            #pragma unroll
            for (int nb = 0; nb < 4; ++nb)
                po[row * 64 + nb * 16 + l16] = f2bf(oacc[nb][r]);
            if (l16 == 0) pL[tb * 64 + row] = lacc[r];
        }
    };

    // pre-issue tile t0
    {
        const int kt0 = (t0 >= p0len) ? (t0 - p0len) : t0;
        stageKV(kt0, t0 & 1);
    }

    for (int t = t0; t < t1; ++t) {
        const int buf = t & 1;
        __syncthreads();                   // drains vmcnt: tile t visible

        if (t + 1 < t1) {
            const int t2 = t + 1;
            stageKV((t2 >= p0len) ? (t2 - p0len) : t2, t2 & 1);
        }

        // phase transition (h=1 only): flush qtBig partial, reset, re-load aq
        if (t == p0len) {
            flushPartial();
            f4_t z = {0.f, 0.f, 0.f, 0.f};
            #pragma unroll
            for (int j = 0; j < 4; ++j) oacc[j] = z;
            lacc = z;
            const size_t qrow = (size_t)(qtSmall * 64 + w * 16 + l16) * 64;
            aq[0] = *(const bf8_t*)(Qp + qrow + quad * 8);
            aq[1] = *(const bf8_t*)(Qp + qrow + 32 + quad * 8);
        }

        const bool ph1 = (t >= p0len);
        const int  kt  = ph1 ? (t - p0len) : t;
        const int  qtc = ph1 ? qtSmall : qtBig;
        const bool diag = (kt == qtc);

        // S = Q K^T (this wave's 16 rows)
        f4_t sacc[4];
        {
            f4_t z = {0.f, 0.f, 0.f, 0.f};
            #pragma unroll
            for (int j = 0; j < 4; ++j) sacc[j] = z;
        }
        #pragma unroll
        for (int ks = 0; ks < 2; ++ks) {
            #pragma unroll
            for (int nb = 0; nb < 4; ++nb) {
                bf8_t bk = *(const bf8_t*)&Ks[buf][(nb * 16 + l16) * 64 + ((((ks << 2) | quad) ^ sw) << 3)];
                sacc[nb] = __builtin_amdgcn_mfma_f32_16x16x32_bf16(aq[ks], bk, sacc[nb], 0, 0, 0);
            }
        }

        // fixed-max softmax: p = exp2(s*0.125*log2e - 14*log2e); trunc-round P.
        // P stored XOR-swizzled: block' = block ^ (row&7).
        // diag is wave-uniform -> mask cost only on the 1 diagonal tile.
        if (!diag) {
            #pragma unroll
            for (int r = 0; r < 4; ++r) {
                const int rloc = (w << 4) + (quad << 2) + r;
                const int rk = rloc & 7;
                #pragma unroll
                for (int nb = 0; nb < 4; ++nb) {
                    union { float f; unsigned int u; } pv;
                    pv.f = exp2f(fmaf(sacc[nb][r], 0.18033688f, -20.197731f));
                    Ps[rloc * 64 + ((((nb << 1) | (l16 >> 3)) ^ rk) << 3) + (l16 & 7)] =
                        (unsigned short)(pv.u >> 16);
                }
            }
        } else {
            #pragma unroll
            for (int r = 0; r < 4; ++r) {
                const int rloc = (w << 4) + (quad << 2) + r;
                const int rk = rloc & 7;
                #pragma unroll
                for (int nb = 0; nb < 4; ++nb) {
                    float e = fmaf(sacc[nb][r], 0.18033688f, -20.197731f);
                    if (nb * 16 + l16 > rloc) e = -1e30f;   // causal
                    union { float f; unsigned int u; } pv;
                    pv.f = exp2f(e);
                    Ps[rloc * 64 + ((((nb << 1) | (l16 >> 3)) ^ rk) << 3) + (l16 & 7)] =
                        (unsigned short)(pv.u >> 16);
                }
            }
        }

        // O += P V ; l += P . 1
        #pragma unroll
        for (int ks = 0; ks < 2; ++ks) {
            bf8_t ap = *(const bf8_t*)&Ps[(w * 16 + l16) * 64 + ((((ks << 2) | quad) ^ sw) << 3)];
            #pragma unroll
            for (int nb = 0; nb < 4; ++nb) {
                bf8_t bv = *(const bf8_t*)&Vs[buf][(nb * 16 + l16) * 64 + ((((ks << 2) | quad) ^ sw) << 3)];
                oacc[nb] = __builtin_amdgcn_mfma_f32_16x16x32_bf16(ap, bv, oacc[nb], 0, 0, 0);
            }
            lacc = __builtin_amdgcn_mfma_f32_16x16x32_bf16(ap, bones, lacc, 0, 0, 0);
        }
    }

    if (!h) {
        flushPartial();                    // h0: qtBig partial
    } else {
        // h1: qtSmall complete -> normalize and write direct
        #pragma unroll
        for (int r = 0; r < 4; ++r) {
            const float lsum = __shfl(lacc[r], lane & 48);
            const float rl = 1.f / lsum;
            const int sq = qtSmall * 64 + (w << 4) + (quad << 2) + r;
            #pragma unroll
            for (int nb = 0; nb < 4; ++nb) {
                const int dcol = head * 64 + nb * 16 + l16;
                ao[((size_t)(b * 2048 + sq)) * 1024 + dcol] = f2bf(oacc[nb][r] * rl);
            }
        }
    }
}

// ---- merge the two qtBig partials: O = (O0+O1)/(l0+l1) -> ao ----
__global__ void merge_kernel(const unsigned short* __restrict__ pO,
                             const float* __restrict__ pL,
                             unsigned short* __restrict__ ao) {
    const int blk  = blockIdx.x;        // 0..511 = bh*16 + jj
    const int bh   = blk >> 4;
    const int jj   = blk & 15;
    const int b    = bh >> 4;
    const int head = bh & 15;
    const int qt   = 31 - jj;
    const int row  = threadIdx.x >> 2;          // 0..63
    const int c0   = (threadIdx.x & 3) << 4;    // 0,16,32,48

    const float l = pL[blk * 64 + row] + pL[(512 + blk) * 64 + row];
    const float rl = 1.f / l;
    const unsigned short* p0 = pO + (size_t)blk * 4096 + row * 64 + c0;
    const unsigned short* p1 = pO + (size_t)(512 + blk) * 4096 + row * 64 + c0;
    unsigned short* dst = ao + ((size_t)(b * 2048 + qt * 64 + row)) * 1024 + head * 64 + c0;
    #pragma unroll
    for (int j = 0; j < 16; ++j)
        dst[j] = f2bf((bf2f(p0[j]) + bf2f(p1[j])) * rl);
}

extern "C" void kernel_launch(void* const* d_in, const int* in_sizes, int n_in,
                              void* d_out, int out_size, void* d_ws, size_t ws_size,
                              hipStream_t stream) {
    const float* x    = (const float*)d_in[0];   // [2,2048,1024]
    const float* Wqkv = (const float*)d_in[1];   // [3072,1024]
    const float* bqkv = (const float*)d_in[2];   // [3072]
    const float* Wd   = (const float*)d_in[3];   // [1024,1024]
    const float* bd   = (const float*)d_in[4];   // [1024]
    float* out = (float*)d_out;                  // [2,2048,1024] fp32

    char* ws = (char*)d_ws;
    unsigned short* xb    = (unsigned short*)(ws);              // 8 MB  [4096][1024] bf16
    unsigned short* wqkvb = (unsigned short*)(ws + 8388608);    // 6 MB  [3072][1024]
    unsigned short* wdb   = (unsigned short*)(ws + 14680064);   // 2 MB  [1024][1024]
    unsigned short* qb2   = (unsigned short*)(ws + 16777216);   // 8 MB  [32][2048][64]
    unsigned short* kb2   = (unsigned short*)(ws + 25165824);   // 8 MB  [32][2048][64]
    unsigned short* vtb   = (unsigned short*)(ws + 33554432);   // 8 MB  [32][64][2048]
    unsigned short* pO    = (unsigned short*)(ws + 41943040);   // 8 MB  [2][512][4096] bf16
    float*          pL    = (float*)(ws + 50331648);            // 256KB [2][512][64] fp32
    unsigned short* ao    = xb;  // reuse x's bf16 buffer after QKV GEMM: [4096][1024]

    cvt_kernel<<<8192, 256, 0, stream>>>(x, xb, Wqkv, wqkvb, Wd, wdb);

    // QKV: [4096,3072] = xb [4096,1024] @ wqkvb^T + bqkv, scattered to q/k/vT
    qkv_gemm<<<dim3(24, 32), 256, 0, stream>>>(
        xb, wqkvb, bqkv, qb2, kb2, vtb, 1024, 3072);

    // causal flash attention (split-K halves, pair-balanced, XCD-swizzled)
    attn_kernel<<<1024, 256, 0, stream>>>(qb2, kb2, vtb, ao, pO, pL);

    // merge qtBig partials into ao
    merge_kernel<<<512, 256, 0, stream>>>(pO, pL, ao);

    // out = ao @ wdb^T + bd  (fp32 out)
    proj_gemm<<<dim3(8, 64), 256, 0, stream>>>(
        ao, wdb, bd, out, 1024, 1024);
}